// Round 8
// baseline (37.951 us; speedup 1.0000x reference)
//
#include <hip/hip_runtime.h>

// Problem: B=64, C=3, S=384, P=32, R=169
//   out0: patches (B*R, C, P, P) f32 -> 33,226,752 elems
//   out1: pos     (B, R, 2)      f32 -> 21,632 elems (flat after patches)
//
// out[b,r,c,i,j] = bilinear sample of x[b,c,·,·] at
//   row = (j + crop_left[b,r]) * scale   (j = output fast axis)
//   col = (i + crop_top [b,r]) * scale
// scale = 383/384 < 1. Verified R1-R7: 33-row window at floor(crop*scale)
// always in-bounds; clamp never binds. absmax 0.016 vs thr 7.04.
//
// R8 = R7 (37.5us best: separable x-lerp at load, reg-MLP taps, f4 nt
// stores) + 2-patch software pipeline per block: patch p1's tap loads are
// issued BEFORE the barrier and consumed AFTER phaseB(p0), so their latency
// hides under compute. Barriers are lgkmcnt-only (raw s_barrier) to avoid
// the compiler's vmcnt(0) drain that would expose the prefetch (m97 stall).
// Pairs are consecutive pr -> same image -> L2/L3 locality kept (R6 fix).
#define Bn 64
#define Cn 3
#define Sn 384
#define Pn 32
#define Rn 169
#define HROWS 33
#define HPLANE (Pn * HROWS)            // 1056 dwords per channel
#define HBUF (Cn * HPLANE)             // 3168 dwords per buffer
#define PATCH_ELEMS (Cn * Pn * Pn)     // 3072
#define POS_OFFSET ((size_t)Bn * Rn * Cn * Pn * Pn)  // 33226752
#define PER_XCD 1352                   // 10816 / 8 (even -> pairs don't split)
#define SCALE (383.0f / 384.0f)
#define CSS (Cn * Sn * Sn)

typedef float f4 __attribute__((ext_vector_type(4)));

// lgkm-only barrier: drain LDS ops, sync waves, do NOT drain vmcnt (keeps
// prefetched global loads in flight across the barrier).
__device__ __forceinline__ void lds_barrier() {
    asm volatile("s_waitcnt lgkmcnt(0)" ::: "memory");
    __builtin_amdgcn_s_barrier();
    __builtin_amdgcn_sched_barrier(0);
}

// Phase B: out(c,i2,jq..jq+3) = owy*H[i2][y0] + wy*H[i2][y0+1].
// Read bank (i2 + y)%32 ~ 2 lanes/bank (free). One ds_read2 + 2 fma/output.
__device__ __forceinline__ void phase_b(
    const float* Hb, float* __restrict__ out, int pr, float clf, int row_base,
    int i2, int jq)
{
    float wyv[4], owyv[4];
    int   yv[4];
    #pragma unroll
    for (int jj = 0; jj < 4; ++jj) {
        float cy = ((float)(jq + jj) + clf) * SCALE;
        float fy = floorf(cy);
        wyv[jj]  = cy - fy;
        owyv[jj] = 1.0f - wyv[jj];
        yv[jj]   = (int)fy - row_base;   // in [0,31]; +1 <= 32 < HROWS
    }
    float* outp = out + (size_t)pr * PATCH_ELEMS + i2 * Pn + jq;
    #pragma unroll
    for (int c = 0; c < Cn; ++c) {
        const float* Hc = Hb + c * HPLANE + i2 * HROWS;
        f4 v;
        #pragma unroll
        for (int jj = 0; jj < 4; ++jj) {
            float h0 = Hc[yv[jj]];       // } ds_read2_b32 (offsets 0,1)
            float h1 = Hc[yv[jj] + 1];   // }
            v[jj] = owyv[jj] * h0 + wyv[jj] * h1;
        }
        // wave = 8 i2-groups x 8 jq-lanes x 16B = 1KB contiguous, stream-once
        __builtin_nontemporal_store(v, (f4*)(outp + c * (Pn * Pn)));
    }
}

__global__ __launch_bounds__(256) void patch_kernel(
    const float* __restrict__ x,         // (B, C, S, S)
    const int*   __restrict__ crop_top,  // (B, R) -> column axis (i)
    const int*   __restrict__ crop_left, // (B, R) -> row axis (j)
    float*       __restrict__ out)
{
    __shared__ float H[2][HBUF];         // 25344 B

    const int bid = blockIdx.x;
    const int xcd = bid & 7;             // HW round-robins blocks over XCDs
    const int idx = bid >> 3;            // 0..675, contiguous per XCD
    const int pr0 = xcd * PER_XCD + idx * 2;
    const int pr1 = pr0 + 1;
    const int t   = threadIdx.x;
    const int i   = t & 31;              // phase-A column lane
    const int g   = t >> 5;              // phase-A row group 0..7
    const int jq  = (t & 7) << 2;        // phase-B j-quad
    const int i2  = t >> 3;              // phase-B column

    // Per-patch params (uniform -> scalar regs)
    const int ct0 = crop_top[pr0], cl0 = crop_left[pr0];
    const int ct1 = crop_top[pr1], cl1 = crop_left[pr1];
    const float ctf0 = (float)ct0, clf0 = (float)cl0;
    const float ctf1 = (float)ct1, clf1 = (float)cl1;
    const int rb0 = (int)floorf(clf0 * SCALE);
    const int rb1 = (int)floorf(clf1 * SCALE);
    const int b0 = pr0 / Rn, b1 = pr1 / Rn;

    // ---- A(p0): 24 tap loads -> regs (MLP), lerp, ds_write H[0] ----
    {
        float cx  = ((float)i + ctf0) * SCALE;
        float fx  = floorf(cx);
        float wx  = cx - fx, owx = 1.0f - wx;
        const float* basep = x + (size_t)b0 * CSS + (int)fx;
        const float* rp    = basep + (rb0 + 4 * g) * Sn;
        float a0[Cn][4], a1[Cn][4];
        #pragma unroll
        for (int c = 0; c < Cn; ++c) {
            const float* p = rp + c * (Sn * Sn);
            #pragma unroll
            for (int k = 0; k < 4; ++k) {
                a0[c][k] = p[k * Sn];
                a1[c][k] = p[k * Sn + 1];
            }
        }
        float e0[Cn], e1[Cn];
        if (t < 32) {                    // row 32 tail, wave 0 only
            const float* p = basep + (rb0 + 32) * Sn;
            #pragma unroll
            for (int c = 0; c < Cn; ++c) {
                e0[c] = p[c * (Sn * Sn)];
                e1[c] = p[c * (Sn * Sn) + 1];
            }
        }
        // write bank (i+4g+k)%32 -> 2 lanes/bank (free); pairs -> ds_write2
        float* Hw = H[0] + i * HROWS + 4 * g;
        #pragma unroll
        for (int c = 0; c < Cn; ++c)
            #pragma unroll
            for (int k = 0; k < 4; ++k)
                Hw[c * HPLANE + k] = owx * a0[c][k] + wx * a1[c][k];
        if (t < 32) {
            #pragma unroll
            for (int c = 0; c < Cn; ++c)
                H[0][c * HPLANE + t * HROWS + 32] = owx * e0[c] + wx * e1[c];
        }
    }

    // ---- Prefetch p1 taps (issue now; consumed after phaseB(p0)) ----
    float cx1  = ((float)i + ctf1) * SCALE;
    float fx1  = floorf(cx1);
    float wx1  = cx1 - fx1, owx1 = 1.0f - wx1;
    const float* basep1 = x + (size_t)b1 * CSS + (int)fx1;
    const float* rp1    = basep1 + (rb1 + 4 * g) * Sn;
    float c0[Cn][4], c1[Cn][4];
    #pragma unroll
    for (int c = 0; c < Cn; ++c) {
        const float* p = rp1 + c * (Sn * Sn);
        #pragma unroll
        for (int k = 0; k < 4; ++k) {
            c0[c][k] = p[k * Sn];
            c1[c][k] = p[k * Sn + 1];
        }
    }
    float f0[Cn], f1[Cn];
    if (t < 32) {
        const float* p = basep1 + (rb1 + 32) * Sn;
        #pragma unroll
        for (int c = 0; c < Cn; ++c) {
            f0[c] = p[c * (Sn * Sn)];
            f1[c] = p[c * (Sn * Sn) + 1];
        }
    }
    // pos outputs ride in the load shadow
    if (t < 2) {
        out[POS_OFFSET + (size_t)pr0 * 2 + t] = (t == 0) ? ctf0 : clf0;
        out[POS_OFFSET + (size_t)pr1 * 2 + t] = (t == 0) ? ctf1 : clf1;
    }

    lds_barrier();                       // H[0] ready; p1 loads stay in flight

    // ---- Phase B(p0): compute+store while p1 loads land ----
    phase_b(H[0], out, pr0, clf0, rb0, i2, jq);

    // ---- A(p1): lerp (vmcnt waits here, mostly satisfied) -> H[1] ----
    {
        float* Hw = H[1] + i * HROWS + 4 * g;
        #pragma unroll
        for (int c = 0; c < Cn; ++c)
            #pragma unroll
            for (int k = 0; k < 4; ++k)
                Hw[c * HPLANE + k] = owx1 * c0[c][k] + wx1 * c1[c][k];
        if (t < 32) {
            #pragma unroll
            for (int c = 0; c < Cn; ++c)
                H[1][c * HPLANE + t * HROWS + 32] = owx1 * f0[c] + wx1 * f1[c];
        }
    }

    lds_barrier();                       // H[1] ready

    // ---- Phase B(p1) ----
    phase_b(H[1], out, pr1, clf1, rb1, i2, jq);
}

extern "C" void kernel_launch(void* const* d_in, const int* in_sizes, int n_in,
                              void* d_out, int out_size, void* d_ws, size_t ws_size,
                              hipStream_t stream) {
    const float* x         = (const float*)d_in[0];
    const int*   crop_top  = (const int*)d_in[1];
    const int*   crop_left = (const int*)d_in[2];
    float*       out       = (float*)d_out;

    patch_kernel<<<dim3(8 * (PER_XCD / 2)), dim3(256), 0, stream>>>(
        x, crop_top, crop_left, out);
}